// Round 1
// baseline (718.885 us; speedup 1.0000x reference)
//
#include <hip/hip_runtime.h>
#include <math.h>

#define NB 128
#define NH 1024
#define NL 512
#define OC 64
#define NE 8
#define ND 1024
#define CAPACITY 24

// ---- workspace layout (float offsets) ----
static const size_t WS_PART  = 0;          // [8][128][1024] pooled-x partials; later GEMM partials [256][8192]
static const size_t WS_PXT   = 2097152;    // pooled_xT [1024][128]
static const size_t WS_HPOOL = 2228224;    // h_pool [128][1024]
static const size_t WS_SCALE = 2359296;    // [1024]
static const size_t WS_SHIFT = 2360320;    // [1024]
static const size_t WS_A1    = 2361344;    // [128][128]
static const size_t WS_TKW   = 2377728;    // [128][8]
static const size_t WS_TKI   = 2378752;    // int [128][8]
static const size_t WS_MAXK  = 2379776;    // int
static const size_t WS_USAGE = 2379784;    // [8]
static const size_t WS_VARU  = 2379792;
static const size_t WS_REG   = 2379793;
static const size_t WS_CNT   = 2379794;    // [8]
static const size_t WS_KEEP  = 2379802;    // int [1024]
static const size_t WS_WMAT  = 2380832;    // [128][8]

__device__ __forceinline__ float gelu_exact(float v) {
    return 0.5f * v * (1.0f + erff(v * 0.70710678118654752440f));
}

__global__ void k_init(float* ws) { ws[WS_REG] = 0.0f; }

// ---- conv1d(H->64,k3,p1) + exact GELU + avgpool(32) ; fused pooled-x partial sums ----
__global__ __launch_bounds__(256) void k_conv(const float* __restrict__ x,
                                              const float* __restrict__ cw,
                                              const float* __restrict__ cb,
                                              float* __restrict__ ws)
{
    const int lc = blockIdx.x;   // 0..7  (64-wide l chunk)
    const int b  = blockIdx.y;   // 0..127
    const int l0 = lc * 64;
    const int tid = threadIdx.x;
    const int o  = tid & 63;     // out channel
    const int lg = tid >> 6;     // wave id = l-group (16 l each)

    __shared__ float xs[32 * 68];     // x tile [32 h][66(+pad2)]
    __shared__ float wsm[32 * 193];   // w tile [32 h][64 o * 3] padded stride 193
    __shared__ float red[64 * 4];
    __shared__ float xsum[8 * 32];    // [part][h]

    float acc[16];
#pragma unroll
    for (int i = 0; i < 16; i++) acc[i] = 0.0f;

    float* part = ws + WS_PART + (size_t)(lc * 128 + b) * 1024;

    for (int ht = 0; ht < NH; ht += 32) {
        __syncthreads();
        // load x tile: rows h, cols l0-1 .. l0+64 (zero pad)
        for (int idx = tid; idx < 32 * 66; idx += 256) {
            int r = idx / 66, c = idx - r * 66;
            int l = l0 - 1 + c;
            float v = 0.0f;
            if (l >= 0 && l < NL) v = x[((size_t)b * NH + ht + r) * NL + l];
            xs[r * 68 + c] = v;
        }
        // load w tile: cw[o][ht+hh][j] -> wsm[hh*193 + o*3 + j]
        for (int idx = tid; idx < 64 * 96; idx += 256) {
            int oo = idx / 96, t = idx - oo * 96;  // t = hh*3 + j
            int hh = t / 3, j = t - hh * 3;
            wsm[hh * 193 + oo * 3 + j] = cw[(size_t)oo * 3072 + (size_t)(ht + hh) * 3 + j];
        }
        __syncthreads();

        // pooled-x partial sums over interior l (c = 1..64)
        {
            int r = tid & 31, prt = tid >> 5;
            float s = 0.0f;
#pragma unroll
            for (int i = 0; i < 8; i++) s += xs[r * 68 + 1 + prt * 8 + i];
            xsum[prt * 32 + r] = s;
        }

        // main conv compute: wave-uniform x reads (broadcast), per-lane w reads
        for (int hh = 0; hh < 32; hh++) {
            const float* xr = &xs[hh * 68 + lg * 16];
            float xv[18];
#pragma unroll
            for (int i = 0; i < 18; i++) xv[i] = xr[i];
            const float w0 = wsm[hh * 193 + o * 3 + 0];
            const float w1 = wsm[hh * 193 + o * 3 + 1];
            const float w2 = wsm[hh * 193 + o * 3 + 2];
#pragma unroll
            for (int i = 0; i < 16; i++)
                acc[i] = fmaf(xv[i + 2], w2, fmaf(xv[i + 1], w1, fmaf(xv[i], w0, acc[i])));
        }
        __syncthreads();
        if (tid < 32) {
            float s = 0.0f;
#pragma unroll
            for (int p = 0; p < 8; p++) s += xsum[p * 32 + tid];
            part[ht + tid] = s;
        }
    }

    // bias + exact GELU + pool partial (16 l per thread, bucket = lg>>1)
    const float bo = cb[o];
    float sacc = 0.0f;
#pragma unroll
    for (int i = 0; i < 16; i++) sacc += gelu_exact(acc[i] + bo);
    red[o * 4 + lg] = sacc;
    __syncthreads();
    if (tid < 128) {
        int oo = tid & 63, p = tid >> 6;
        float v = (red[oo * 4 + 2 * p] + red[oo * 4 + 2 * p + 1]) * (1.0f / 32.0f);
        ws[WS_HPOOL + (size_t)b * 1024 + oo * 16 + lc * 2 + p] = v;
    }
}

// ---- reduce pooled-x partials -> pooled_xT[h][b] ----
__global__ __launch_bounds__(256) void k_poolx(float* __restrict__ ws)
{
    int id = blockIdx.x * 256 + threadIdx.x;   // 131072
    int b = id >> 10, h = id & 1023;
    float s = 0.0f;
#pragma unroll
    for (int lcc = 0; lcc < 8; lcc++) s += ws[WS_PART + ((size_t)(lcc * 128 + b)) * 1024 + h];
    ws[WS_PXT + (size_t)h * 128 + b] = s * (1.0f / 512.0f);
}

// ---- batch-norm stats (training mode, batch stats, ddof=0) -> scale/shift ----
__global__ __launch_bounds__(256) void k_bn(const float* __restrict__ g,
                                            const float* __restrict__ bet,
                                            float* __restrict__ ws)
{
    int f = blockIdx.x * 256 + threadIdx.x;    // 1024
    const float* hp = ws + WS_HPOOL;
    float s = 0.0f;
    for (int b = 0; b < 128; b++) s += hp[(size_t)b * 1024 + f];
    float mu = s * (1.0f / 128.0f);
    float v = 0.0f;
    for (int b = 0; b < 128; b++) { float d = hp[(size_t)b * 1024 + f] - mu; v += d * d; }
    float var = v * (1.0f / 128.0f);
    float sc = g[f] / sqrtf(var + 1e-5f);
    ws[WS_SCALE + f] = sc;
    ws[WS_SHIFT + f] = bet[f] - mu * sc;
}

// ---- FC1 (1024->128) + exact GELU ----
__global__ __launch_bounds__(128) void k_fc1(const float* __restrict__ w1,
                                             const float* __restrict__ b1,
                                             float* __restrict__ ws)
{
    __shared__ float hb[1024];
    int b = blockIdx.x, tid = threadIdx.x;
    const float* hp = ws + WS_HPOOL + (size_t)b * 1024;
    for (int k = tid; k < 1024; k += 128)
        hb[k] = hp[k] * ws[WS_SCALE + k] + ws[WS_SHIFT + k];
    __syncthreads();
    const float4* wr = (const float4*)(w1 + (size_t)tid * 1024);
    float acc = 0.0f;
#pragma unroll 4
    for (int k = 0; k < 256; k++) {
        float4 w = wr[k];
        const float* h4 = &hb[k * 4];
        acc = fmaf(h4[0], w.x, acc); acc = fmaf(h4[1], w.y, acc);
        acc = fmaf(h4[2], w.z, acc); acc = fmaf(h4[3], w.w, acc);
    }
    float v = acc + b1[tid];
    ws[WS_A1 + (size_t)b * 128 + tid] = gelu_exact(v);
}

// ---- FC2 + softmax + stable top-k sort + dynamic k + usage/var ----
__global__ __launch_bounds__(128) void k_router(const float* __restrict__ w2,
                                                const float* __restrict__ b2,
                                                float* __restrict__ ws)
{
    __shared__ float w2s[1024];
    __shared__ float red[1024];
    __shared__ float usg[8];
    __shared__ int mk;
    int tid = threadIdx.x;
    for (int i = tid; i < 1024; i += 128) w2s[i] = w2[i];
    if (tid == 0) mk = 0;
    __syncthreads();

    const int b = tid;
    const float* ar = ws + WS_A1 + (size_t)b * 128;
    float rw[8];
    float m = -1e30f;
#pragma unroll
    for (int e = 0; e < 8; e++) {
        float acc = b2[e];
        for (int k = 0; k < 128; k++) acc = fmaf(ar[k], w2s[e * 128 + k], acc);
        rw[e] = acc;
        m = fmaxf(m, acc);
    }
    float s = 0.0f;
#pragma unroll
    for (int e = 0; e < 8; e++) { rw[e] = expf(rw[e] - m); s += rw[e]; }
    float inv = 1.0f / s;
#pragma unroll
    for (int e = 0; e < 8; e++) rw[e] *= inv;

#pragma unroll
    for (int e = 0; e < 8; e++) red[e * 128 + b] = rw[e];

    // stable descending selection sort (ties -> lower index first, like lax.top_k)
    float tw[8]; int ti[8]; unsigned used = 0;
#pragma unroll
    for (int r = 0; r < 8; r++) {
        float bv = -1e30f; int bi = 0;
#pragma unroll
        for (int e = 0; e < 8; e++) {
            bool take = !((used >> e) & 1u) && (rw[e] > bv);
            bv = take ? rw[e] : bv;
            bi = take ? e : bi;
        }
        used |= (1u << bi);
        tw[r] = bv; ti[r] = bi;
    }
    float cum = 0.0f; int kp = 8;
#pragma unroll
    for (int r = 0; r < 8; r++) {
        cum += tw[r];
        if (cum > 0.8f) { kp = r + 1; break; }
    }
    atomicMax(&mk, kp);
#pragma unroll
    for (int r = 0; r < 8; r++) {
        ws[WS_TKW + b * 8 + r] = tw[r];
        ((int*)ws)[WS_TKI + b * 8 + r] = ti[r];
    }
    __syncthreads();
    if (tid < 8) {
        float s2 = 0.0f;
        for (int bb = 0; bb < 128; bb++) s2 += red[tid * 128 + bb];
        float u = s2 * (1.0f / 128.0f);
        usg[tid] = u;
        ws[WS_USAGE + tid] = u;
    }
    if (tid == 0) ((int*)ws)[WS_MAXK] = mk;
    __syncthreads();
    if (tid == 0) {
        float mu = 0.0f;
#pragma unroll
        for (int e = 0; e < 8; e++) mu += usg[e];
        mu *= (1.0f / 8.0f);
        float v = 0.0f;
#pragma unroll
        for (int e = 0; e < 8; e++) { float d = usg[e] - mu; v += d * d; }
        ws[WS_VARU] = v * (1.0f / 7.0f);   // ddof=1
    }
}

// ---- per-expert capacity ranking (stable: greater weight, tie -> smaller flat slot) ----
__global__ __launch_bounds__(128) void k_cap(float* __restrict__ ws)
{
    __shared__ float wv[128];
    __shared__ int sv[128];
    __shared__ int cnt;
    const int e = blockIdx.x, b = threadIdx.x;
    const int maxk = ((const int*)ws)[WS_MAXK];
    const float* tkw = ws + WS_TKW;
    const int* tki = (const int*)ws + WS_TKI;

    float myw = 0.0f; int mys = -1;
    for (int k = 0; k < maxk; k++) {
        if (tki[b * 8 + k] == e) { myw = tkw[b * 8 + k]; mys = b * 8 + k; }
    }
    wv[b] = myw; sv[b] = mys;
    if (b == 0) cnt = 0;
    __syncthreads();
    int kept = 0;
    if (mys >= 0) {
        int rank = 0;
        for (int b2 = 0; b2 < 128; b2++) {
            int s2 = sv[b2];
            if (s2 >= 0) {
                float w2 = wv[b2];
                if (w2 > myw || (w2 == myw && s2 < mys)) rank++;
            }
        }
        kept = (rank < CAPACITY) ? 1 : 0;
        ((int*)ws)[WS_KEEP + mys] = kept;
    }
    atomicAdd(&cnt, kept);
    __syncthreads();
    if (b == 0) ws[WS_CNT + e] = (float)cnt;
}

// ---- combine weights: softmax over slots (dropped -> logit 0), W[b][e] ----
__global__ __launch_bounds__(128) void k_comb(float* __restrict__ ws)
{
    const int b = threadIdx.x;
    const int maxk = ((const int*)ws)[WS_MAXK];
    const float* tkw = ws + WS_TKW;
    const int* tki = (const int*)ws + WS_TKI;
    const int* keep = (const int*)ws + WS_KEEP;

    float lv[8]; int kept[8]; int idx[8];
#pragma unroll
    for (int k = 0; k < 8; k++) {
        if (k < maxk) {
            kept[k] = keep[b * 8 + k];
            idx[k] = tki[b * 8 + k];
            lv[k] = kept[k] ? tkw[b * 8 + k] : 0.0f;
        } else { kept[k] = 0; idx[k] = -1; lv[k] = -1e30f; }
    }
    float mx = -1e30f;
#pragma unroll
    for (int k = 0; k < 8; k++) if (k < maxk) mx = fmaxf(mx, lv[k]);
    float s = 0.0f; float ev[8];
#pragma unroll
    for (int k = 0; k < 8; k++) { ev[k] = (k < maxk) ? expf(lv[k] - mx) : 0.0f; s += ev[k]; }
    float inv = 1.0f / s;
    float Wr[8] = {0, 0, 0, 0, 0, 0, 0, 0};
#pragma unroll
    for (int k = 0; k < 8; k++) {
        if (kept[k]) {
            float v = ev[k] * inv;
#pragma unroll
            for (int e = 0; e < 8; e++) Wr[e] += (idx[k] == e) ? v : 0.0f;
        }
    }
#pragma unroll
    for (int e = 0; e < 8; e++) ws[WS_WMAT + b * 8 + e] = Wr[e];
}

// ---- L2 regularizer: sum(exp_w^2) + sum(exp_b^2) ----
__global__ __launch_bounds__(256) void k_reg(const float* __restrict__ ew,
                                             const float* __restrict__ eb,
                                             float* __restrict__ ws)
{
    __shared__ float red[256];
    const size_t t0 = (size_t)blockIdx.x * 256 + threadIdx.x;
    const size_t stride = (size_t)gridDim.x * 256 * 4;
    float s = 0.0f;
    for (size_t i = t0 * 4; i < 8388608; i += stride) {
        float4 v = *(const float4*)(ew + i);
        s += v.x * v.x + v.y * v.y + v.z * v.z + v.w * v.w;
    }
    if (t0 < 2048) {
        float4 v = ((const float4*)eb)[t0];
        s += v.x * v.x + v.y * v.y + v.z * v.z + v.w * v.w;
    }
    red[threadIdx.x] = s;
    __syncthreads();
    for (int off = 128; off > 0; off >>= 1) {
        if (threadIdx.x < off) red[threadIdx.x] += red[threadIdx.x + off];
        __syncthreads();
    }
    if (threadIdx.x == 0) atomicAdd(ws + WS_REG, red[0]);
}

// ---- expert mix GEMM: part[ks][dt][b][dd] = sum_k (W[b,e]*pxT[h,b]) * exp_w[k, d]  (split-K=16) ----
__global__ __launch_bounds__(256) void k_gemm(const float* __restrict__ ew,
                                              float* __restrict__ ws)
{
    __shared__ float a_s[32 * 128];
    __shared__ float b_s[32 * 64];
    __shared__ float w_s[1024];
    const int blk = blockIdx.x;
    const int ks = blk >> 4, dt = blk & 15;
    const int tid = threadIdx.x;
    const int tb = tid >> 3, td = tid & 7;   // 32 b-groups(x4) x 8 d-groups(x8)
    for (int i = tid; i < 1024; i += 256) w_s[i] = ws[WS_WMAT + i];
    float acc[4][8];
#pragma unroll
    for (int i = 0; i < 4; i++)
#pragma unroll
        for (int j = 0; j < 8; j++) acc[i][j] = 0.0f;

    const float* pxt = ws + WS_PXT;
    for (int kt = 0; kt < 512; kt += 32) {
        __syncthreads();
        for (int idx = tid; idx < 4096; idx += 256) {
            int kk = idx >> 7, b = idx & 127;
            int k = ks * 512 + kt + kk;
            int e = k >> 10, h = k & 1023;
            a_s[kk * 128 + b] = w_s[b * 8 + e] * pxt[(size_t)h * 128 + b];
        }
        for (int idx = tid; idx < 2048; idx += 256) {
            int kk = idx >> 6, d = idx & 63;
            b_s[kk * 64 + d] = ew[(size_t)(ks * 512 + kt + kk) * 1024 + dt * 64 + d];
        }
        __syncthreads();
#pragma unroll 4
        for (int kk = 0; kk < 32; kk++) {
            float4 av = *(const float4*)&a_s[kk * 128 + tb * 4];
            float4 b0 = *(const float4*)&b_s[kk * 64 + td * 8];
            float4 b1 = *(const float4*)&b_s[kk * 64 + td * 8 + 4];
            float aa[4] = {av.x, av.y, av.z, av.w};
            float bb[8] = {b0.x, b0.y, b0.z, b0.w, b1.x, b1.y, b1.z, b1.w};
#pragma unroll
            for (int i = 0; i < 4; i++)
#pragma unroll
                for (int j = 0; j < 8; j++) acc[i][j] = fmaf(aa[i], bb[j], acc[i][j]);
        }
    }
    float* outp = ws + WS_PART + (size_t)blk * 8192;
#pragma unroll
    for (int i = 0; i < 4; i++) {
        int bb = tb * 4 + i;
        float4 v0 = make_float4(acc[i][0], acc[i][1], acc[i][2], acc[i][3]);
        float4 v1 = make_float4(acc[i][4], acc[i][5], acc[i][6], acc[i][7]);
        *(float4*)(outp + bb * 64 + td * 8) = v0;
        *(float4*)(outp + bb * 64 + td * 8 + 4) = v1;
    }
}

// ---- split-K reduce + weighted expert bias + scalar outputs ----
__global__ __launch_bounds__(256) void k_final(const float* __restrict__ eb,
                                               const float* __restrict__ ws,
                                               float* __restrict__ out)
{
    int id = blockIdx.x * 256 + threadIdx.x;   // 131072
    int b = id >> 10, d = id & 1023;
    int dt = d >> 6, dd = d & 63;
    float s = 0.0f;
#pragma unroll
    for (int ks = 0; ks < 16; ks++)
        s += ws[WS_PART + ((size_t)(ks * 16 + dt) * 128 + b) * 64 + dd];
    float bias = 0.0f;
#pragma unroll
    for (int e = 0; e < 8; e++)
        bias += ws[WS_WMAT + b * 8 + e] * eb[(size_t)e * 1024 + d];
    out[id] = s + bias;
    if (blockIdx.x == 0) {
        int t = threadIdx.x;
        if (t == 0) out[131072] = 0.005f * ws[WS_VARU] + 1e-6f * ws[WS_REG];
        else if (t >= 1 && t < 9)  out[131072 + t] = ws[WS_USAGE + t - 1];
        else if (t >= 9 && t < 17) out[131072 + t] = ws[WS_CNT + t - 9];
    }
}

extern "C" void kernel_launch(void* const* d_in, const int* in_sizes, int n_in,
                              void* d_out, int out_size, void* d_ws, size_t ws_size,
                              hipStream_t stream)
{
    const float* x   = (const float*)d_in[0];
    const float* cw  = (const float*)d_in[1];
    const float* cb  = (const float*)d_in[2];
    const float* bng = (const float*)d_in[3];
    const float* bnb = (const float*)d_in[4];
    const float* f1w = (const float*)d_in[5];
    const float* f1b = (const float*)d_in[6];
    const float* f2w = (const float*)d_in[7];
    const float* f2b = (const float*)d_in[8];
    const float* ew  = (const float*)d_in[9];
    const float* eb  = (const float*)d_in[10];
    float* ws  = (float*)d_ws;
    float* out = (float*)d_out;

    k_init  <<<1, 1, 0, stream>>>(ws);
    k_conv  <<<dim3(8, 128), 256, 0, stream>>>(x, cw, cb, ws);
    k_poolx <<<512, 256, 0, stream>>>(ws);
    k_bn    <<<4, 256, 0, stream>>>(bng, bnb, ws);
    k_fc1   <<<128, 128, 0, stream>>>(f1w, f1b, ws);
    k_router<<<1, 128, 0, stream>>>(f2w, f2b, ws);
    k_cap   <<<8, 128, 0, stream>>>(ws);
    k_comb  <<<1, 128, 0, stream>>>(ws);
    k_reg   <<<512, 256, 0, stream>>>(ew, eb, ws);
    k_gemm  <<<256, 256, 0, stream>>>(ew, ws);
    k_final <<<512, 256, 0, stream>>>(eb, ws, out);
}

// Round 2
// 375.068 us; speedup vs baseline: 1.9167x; 1.9167x over previous
//
#include <hip/hip_runtime.h>
#include <hip/hip_bf16.h>
#include <math.h>

#define NB 128
#define NH 1024
#define NL 512
#define OC 64
#define NE 8
#define ND 1024
#define CAPACITY 24

// ---- workspace layout (float offsets) ----
static const size_t WS_PART  = 0;          // [4][128][1024] pooled-x partials; later GEMM partials [256][8192]
static const size_t WS_WSEP  = 1048576;    // bf16 split weights [2][3][64][1024] ushort (inside PART region, consumed before k_gemm clobbers)
static const size_t WS_PXT   = 2097152;    // pooled_xT [1024][128]
static const size_t WS_HPOOL = 2228224;    // h_pool [128][1024]
static const size_t WS_SCALE = 2359296;    // [1024]
static const size_t WS_SHIFT = 2360320;    // [1024]
static const size_t WS_A1    = 2361344;    // [128][128]
static const size_t WS_TKW   = 2377728;    // [128][8]
static const size_t WS_TKI   = 2378752;    // int [128][8]
static const size_t WS_MAXK  = 2379776;    // int
static const size_t WS_USAGE = 2379784;    // [8]
static const size_t WS_VARU  = 2379792;
static const size_t WS_REG   = 2379793;
static const size_t WS_CNT   = 2379794;    // [8]
static const size_t WS_KEEP  = 2379802;    // int [1024]
static const size_t WS_WMAT  = 2380832;    // [128][8]

typedef __attribute__((ext_vector_type(8))) short bf16x8;
typedef __attribute__((ext_vector_type(4))) float f32x4;

__device__ __forceinline__ float gelu_exact(float v) {
    return 0.5f * v * (1.0f + erff(v * 0.70710678118654752440f));
}

__device__ __forceinline__ unsigned short f2bf_rne(float f) {
    unsigned int u = __float_as_uint(f);
    unsigned int r = u + 0x7FFFu + ((u >> 16) & 1u);
    return (unsigned short)(r >> 16);
}
__device__ __forceinline__ float bf2f(unsigned short h) {
    return __uint_as_float(((unsigned int)h) << 16);
}

__global__ void k_init(float* ws) { ws[WS_REG] = 0.0f; }

// ---- split conv weights into bf16 hi/lo, layout [split][j][o][h] ----
__global__ __launch_bounds__(256) void k_wsplit(const float* __restrict__ cw, float* __restrict__ ws)
{
    unsigned short* wsep = (unsigned short*)(ws + WS_WSEP);
    int i = blockIdx.x * 256 + threadIdx.x;   // 196608
    int j = i % 3; int oh = i / 3; int h = oh & 1023; int o = oh >> 10;
    float v = cw[i];
    unsigned short hi = f2bf_rne(v);
    unsigned short lo = f2bf_rne(v - bf2f(hi));
    size_t dst = ((size_t)j * 64 + o) * 1024 + h;
    wsep[dst] = hi;
    wsep[dst + 196608] = lo;
}

// ---- conv1d via bf16-split MFMA + GELU + pool + fused pooled-x partials ----
// grid (4 lc, 128 b), 256 threads = 4 waves. Block out [64 o][128 l], wave [64 o][32 l].
// LDS x tile: transposed [wcol 136][88 bf16-row] (hi@0, lo@40 dwords-offset 20), 16B-chunk XOR swizzle.
__global__ __launch_bounds__(256, 2) void k_convmfma(const float* __restrict__ x,
                                                     const float* __restrict__ cb,
                                                     float* __restrict__ ws)
{
    __shared__ unsigned short xls[136 * 88];
    __shared__ unsigned short wls[192 * 88];
    __shared__ float xsum[32 * 16];
    __shared__ float scb[64];

    const int lc = blockIdx.x, b = blockIdx.y;
    const int l0 = lc * 128;
    const int tid = threadIdx.x;
    const int wv = tid >> 6, lane = tid & 63;
    const int h2 = tid & 15;          // x-staging h-pair id
    const int slot = tid >> 4;        // x-staging partial slot

    const unsigned int* wsg = (const unsigned int*)(ws + WS_WSEP);
    unsigned int* xlsd = (unsigned int*)xls;
    unsigned int* wlsd = (unsigned int*)wls;

    if (tid < 64) scb[tid] = cb[tid];

    f32x4 acc[4][2];
#pragma unroll
    for (int mt = 0; mt < 4; ++mt)
#pragma unroll
        for (int nt = 0; nt < 2; ++nt) acc[mt][nt] = (f32x4){0.f, 0.f, 0.f, 0.f};

    float4 xa[3], xb[3];
    uint4 wr[6];

    // ---- prologue load (ht = 0) ----
    {
        const int ht = 0;
#pragma unroll
        for (int u = 0; u < 3; ++u) {
            int unit = tid + 256 * u;
            float4 va = {0.f,0.f,0.f,0.f}, vb = {0.f,0.f,0.f,0.f};
            if (unit < 544) {
                int lq = unit >> 4;
                int gl = l0 - 4 + lq * 4;
                if (gl >= 0 && gl < NL) {
                    const float* p = x + ((size_t)b * NH + (ht + 2 * h2)) * NL + gl;
                    va = *(const float4*)p;
                    vb = *(const float4*)(p + NL);
                }
            }
            xa[u] = va; xb[u] = vb;
        }
#pragma unroll
        for (int u = 0; u < 6; ++u) {
            int cu = tid + 256 * u;
            int hpq = cu & 3, run = cu >> 2;
            int o = run & 63, sj = run >> 6;
            wr[u] = *(const uint4*)(wsg + (size_t)(sj * 64 + o) * 512 + (ht >> 1) + hpq * 4);
        }
    }

    for (int it = 0; it < 32; ++it) {
        const int ht = it * 32;
        __syncthreads();

        // ---- write staged regs -> LDS (+ pooled-x partial) ----
        {
            float s0 = 0.f, s1 = 0.f;
#pragma unroll
            for (int u = 0; u < 3; ++u) {
                int unit = tid + 256 * u;
                if (unit < 544) {
                    int lq = unit >> 4;
                    float4 va = xa[u], vb = xb[u];
                    if (lq >= 1 && lq <= 32) {
                        s0 += va.x + va.y + va.z + va.w;
                        s1 += vb.x + vb.y + vb.z + vb.w;
                    }
                    float fa[4] = {va.x, va.y, va.z, va.w};
                    float fb[4] = {vb.x, vb.y, vb.z, vb.w};
#pragma unroll
                    for (int i = 0; i < 4; ++i) {
                        int row = lq * 4 + i;
                        unsigned short ha = f2bf_rne(fa[i]);
                        unsigned short la = f2bf_rne(fa[i] - bf2f(ha));
                        unsigned short hb = f2bf_rne(fb[i]);
                        unsigned short lb = f2bf_rne(fb[i] - bf2f(hb));
                        int cd = ((h2 >> 2) ^ (row & 3)) * 4 + (h2 & 3);
                        xlsd[row * 44 + cd]      = (unsigned int)ha | ((unsigned int)hb << 16);
                        xlsd[row * 44 + 20 + cd] = (unsigned int)la | ((unsigned int)lb << 16);
                    }
                }
            }
            xsum[(2 * h2) * 16 + slot]     = s0;
            xsum[(2 * h2 + 1) * 16 + slot] = s1;
#pragma unroll
            for (int u = 0; u < 6; ++u) {
                int cu = tid + 256 * u;
                int hpq = cu & 3, run = cu >> 2;
                int o = run & 63, sj = run >> 6;
                int split = (sj >= 3) ? 1 : 0;
                int j = sj - 3 * split;
                int row = j * 64 + o;
                int cd = (hpq ^ (o & 3)) * 4;
                *(uint4*)&wlsd[row * 44 + split * 20 + cd] = wr[u];
            }
        }
        __syncthreads();

        // ---- prefetch next step's global loads (latency hides under MFMA) ----
        if (it < 31) {
            const int hn = ht + 32;
#pragma unroll
            for (int u = 0; u < 3; ++u) {
                int unit = tid + 256 * u;
                float4 va = {0.f,0.f,0.f,0.f}, vb = {0.f,0.f,0.f,0.f};
                if (unit < 544) {
                    int lq = unit >> 4;
                    int gl = l0 - 4 + lq * 4;
                    if (gl >= 0 && gl < NL) {
                        const float* p = x + ((size_t)b * NH + (hn + 2 * h2)) * NL + gl;
                        va = *(const float4*)p;
                        vb = *(const float4*)(p + NL);
                    }
                }
                xa[u] = va; xb[u] = vb;
            }
#pragma unroll
            for (int u = 0; u < 6; ++u) {
                int cu = tid + 256 * u;
                int hpq = cu & 3, run = cu >> 2;
                int o = run & 63, sj = run >> 6;
                wr[u] = *(const uint4*)(wsg + (size_t)(sj * 64 + o) * 512 + (hn >> 1) + hpq * 4);
            }
        }

        // ---- pooled-x partial reduce for this h-slice ----
        if (tid < 32) {
            float s = 0.f;
#pragma unroll
            for (int q = 0; q < 16; ++q) s += xsum[tid * 16 + q];
            ws[WS_PART + ((size_t)(lc * 128 + b)) * 1024 + ht + tid] = s;
        }

        // ---- MFMA compute on LDS tile ----
#pragma unroll
        for (int j = 0; j < 3; ++j) {
            bf16x8 Ah[4], Al[4];
#pragma unroll
            for (int mt = 0; mt < 4; ++mt) {
                int row = j * 64 + mt * 16 + (lane & 15);
                int cd = ((lane >> 4) ^ (row & 3)) * 4;
                const unsigned int* bp = wlsd + row * 44 + cd;
                Ah[mt] = *(const bf16x8*)bp;
                Al[mt] = *(const bf16x8*)(bp + 20);
            }
            bf16x8 Bh[2], Bl[2];
#pragma unroll
            for (int nt = 0; nt < 2; ++nt) {
                int rx = 3 + j + wv * 32 + nt * 16 + (lane & 15);
                int cd = ((lane >> 4) ^ (rx & 3)) * 4;
                const unsigned int* bp = xlsd + rx * 44 + cd;
                Bh[nt] = *(const bf16x8*)bp;
                Bl[nt] = *(const bf16x8*)(bp + 20);
            }
#pragma unroll
            for (int mt = 0; mt < 4; ++mt)
#pragma unroll
                for (int nt = 0; nt < 2; ++nt) {
                    acc[mt][nt] = __builtin_amdgcn_mfma_f32_16x16x32_bf16(Ah[mt], Bh[nt], acc[mt][nt], 0, 0, 0);
                    acc[mt][nt] = __builtin_amdgcn_mfma_f32_16x16x32_bf16(Ah[mt], Bl[nt], acc[mt][nt], 0, 0, 0);
                    acc[mt][nt] = __builtin_amdgcn_mfma_f32_16x16x32_bf16(Al[mt], Bh[nt], acc[mt][nt], 0, 0, 0);
                }
        }
    }

    // ---- epilogue: bias + exact GELU + pool(32) ----
    {
        const int g = lane >> 4, cidx = lane & 15;
#pragma unroll
        for (int mt = 0; mt < 4; ++mt) {
            float s[4];
#pragma unroll
            for (int r = 0; r < 4; ++r) {
                int o = mt * 16 + g * 4 + r;
                float bo = scb[o];
                s[r] = gelu_exact(acc[mt][0][r] + bo) + gelu_exact(acc[mt][1][r] + bo);
            }
#pragma unroll
            for (int m = 1; m < 16; m <<= 1) {
#pragma unroll
                for (int r = 0; r < 4; ++r) s[r] += __shfl_xor(s[r], m, 64);
            }
            if (cidx == 0) {
#pragma unroll
                for (int r = 0; r < 4; ++r) {
                    int o = mt * 16 + g * 4 + r;
                    ws[WS_HPOOL + (size_t)b * 1024 + o * 16 + lc * 4 + wv] = s[r] * (1.0f / 32.0f);
                }
            }
        }
    }
}

// ---- reduce pooled-x partials -> pooled_xT[h][b] ----
__global__ __launch_bounds__(256) void k_poolx(float* __restrict__ ws)
{
    int id = blockIdx.x * 256 + threadIdx.x;   // 131072
    int b = id >> 10, h = id & 1023;
    float s = 0.0f;
#pragma unroll
    for (int lcc = 0; lcc < 4; lcc++) s += ws[WS_PART + ((size_t)(lcc * 128 + b)) * 1024 + h];
    ws[WS_PXT + (size_t)h * 128 + b] = s * (1.0f / 512.0f);
}

// ---- batch-norm stats (training mode, batch stats, ddof=0) -> scale/shift ----
__global__ __launch_bounds__(256) void k_bn(const float* __restrict__ g,
                                            const float* __restrict__ bet,
                                            float* __restrict__ ws)
{
    int f = blockIdx.x * 256 + threadIdx.x;    // 1024
    const float* hp = ws + WS_HPOOL;
    float s = 0.0f;
    for (int b = 0; b < 128; b++) s += hp[(size_t)b * 1024 + f];
    float mu = s * (1.0f / 128.0f);
    float v = 0.0f;
    for (int b = 0; b < 128; b++) { float d = hp[(size_t)b * 1024 + f] - mu; v += d * d; }
    float var = v * (1.0f / 128.0f);
    float sc = g[f] / sqrtf(var + 1e-5f);
    ws[WS_SCALE + f] = sc;
    ws[WS_SHIFT + f] = bet[f] - mu * sc;
}

// ---- FC1 (1024->128) + exact GELU ----
__global__ __launch_bounds__(128) void k_fc1(const float* __restrict__ w1,
                                             const float* __restrict__ b1,
                                             float* __restrict__ ws)
{
    __shared__ float hb[1024];
    int b = blockIdx.x, tid = threadIdx.x;
    const float* hp = ws + WS_HPOOL + (size_t)b * 1024;
    for (int k = tid; k < 1024; k += 128)
        hb[k] = hp[k] * ws[WS_SCALE + k] + ws[WS_SHIFT + k];
    __syncthreads();
    const float4* wrp = (const float4*)(w1 + (size_t)tid * 1024);
    float acc = 0.0f;
#pragma unroll 4
    for (int k = 0; k < 256; k++) {
        float4 w = wrp[k];
        const float* h4 = &hb[k * 4];
        acc = fmaf(h4[0], w.x, acc); acc = fmaf(h4[1], w.y, acc);
        acc = fmaf(h4[2], w.z, acc); acc = fmaf(h4[3], w.w, acc);
    }
    float v = acc + b1[tid];
    ws[WS_A1 + (size_t)b * 128 + tid] = gelu_exact(v);
}

// ---- FC2 + softmax + stable top-k sort + dynamic k + usage/var ----
__global__ __launch_bounds__(128) void k_router(const float* __restrict__ w2,
                                                const float* __restrict__ b2,
                                                float* __restrict__ ws)
{
    __shared__ float w2s[1024];
    __shared__ float red[1024];
    __shared__ float usg[8];
    __shared__ int mk;
    int tid = threadIdx.x;
    for (int i = tid; i < 1024; i += 128) w2s[i] = w2[i];
    if (tid == 0) mk = 0;
    __syncthreads();

    const int b = tid;
    const float* ar = ws + WS_A1 + (size_t)b * 128;
    float rw[8];
    float m = -1e30f;
#pragma unroll
    for (int e = 0; e < 8; e++) {
        float acc = b2[e];
        for (int k = 0; k < 128; k++) acc = fmaf(ar[k], w2s[e * 128 + k], acc);
        rw[e] = acc;
        m = fmaxf(m, acc);
    }
    float s = 0.0f;
#pragma unroll
    for (int e = 0; e < 8; e++) { rw[e] = expf(rw[e] - m); s += rw[e]; }
    float inv = 1.0f / s;
#pragma unroll
    for (int e = 0; e < 8; e++) rw[e] *= inv;

#pragma unroll
    for (int e = 0; e < 8; e++) red[e * 128 + b] = rw[e];

    float tw[8]; int ti[8]; unsigned used = 0;
#pragma unroll
    for (int r = 0; r < 8; r++) {
        float bv = -1e30f; int bi = 0;
#pragma unroll
        for (int e = 0; e < 8; e++) {
            bool take = !((used >> e) & 1u) && (rw[e] > bv);
            bv = take ? rw[e] : bv;
            bi = take ? e : bi;
        }
        used |= (1u << bi);
        tw[r] = bv; ti[r] = bi;
    }
    float cum = 0.0f; int kp = 8;
#pragma unroll
    for (int r = 0; r < 8; r++) {
        cum += tw[r];
        if (cum > 0.8f) { kp = r + 1; break; }
    }
    atomicMax(&mk, kp);
#pragma unroll
    for (int r = 0; r < 8; r++) {
        ws[WS_TKW + b * 8 + r] = tw[r];
        ((int*)ws)[WS_TKI + b * 8 + r] = ti[r];
    }
    __syncthreads();
    if (tid < 8) {
        float s2 = 0.0f;
        for (int bb = 0; bb < 128; bb++) s2 += red[tid * 128 + bb];
        float u = s2 * (1.0f / 128.0f);
        usg[tid] = u;
        ws[WS_USAGE + tid] = u;
    }
    if (tid == 0) ((int*)ws)[WS_MAXK] = mk;
    __syncthreads();
    if (tid == 0) {
        float mu = 0.0f;
#pragma unroll
        for (int e = 0; e < 8; e++) mu += usg[e];
        mu *= (1.0f / 8.0f);
        float v = 0.0f;
#pragma unroll
        for (int e = 0; e < 8; e++) { float d = usg[e] - mu; v += d * d; }
        ws[WS_VARU] = v * (1.0f / 7.0f);
    }
}

// ---- per-expert capacity ranking ----
__global__ __launch_bounds__(128) void k_cap(float* __restrict__ ws)
{
    __shared__ float wv[128];
    __shared__ int sv[128];
    __shared__ int cnt;
    const int e = blockIdx.x, b = threadIdx.x;
    const int maxk = ((const int*)ws)[WS_MAXK];
    const float* tkw = ws + WS_TKW;
    const int* tki = (const int*)ws + WS_TKI;

    float myw = 0.0f; int mys = -1;
    for (int k = 0; k < maxk; k++) {
        if (tki[b * 8 + k] == e) { myw = tkw[b * 8 + k]; mys = b * 8 + k; }
    }
    wv[b] = myw; sv[b] = mys;
    if (b == 0) cnt = 0;
    __syncthreads();
    int kept = 0;
    if (mys >= 0) {
        int rank = 0;
        for (int b2 = 0; b2 < 128; b2++) {
            int s2 = sv[b2];
            if (s2 >= 0) {
                float w2 = wv[b2];
                if (w2 > myw || (w2 == myw && s2 < mys)) rank++;
            }
        }
        kept = (rank < CAPACITY) ? 1 : 0;
        ((int*)ws)[WS_KEEP + mys] = kept;
    }
    atomicAdd(&cnt, kept);
    __syncthreads();
    if (b == 0) ws[WS_CNT + e] = (float)cnt;
}

// ---- combine weights ----
__global__ __launch_bounds__(128) void k_comb(float* __restrict__ ws)
{
    const int b = threadIdx.x;
    const int maxk = ((const int*)ws)[WS_MAXK];
    const float* tkw = ws + WS_TKW;
    const int* tki = (const int*)ws + WS_TKI;
    const int* keep = (const int*)ws + WS_KEEP;

    float lv[8]; int kept[8]; int idx[8];
#pragma unroll
    for (int k = 0; k < 8; k++) {
        if (k < maxk) {
            kept[k] = keep[b * 8 + k];
            idx[k] = tki[b * 8 + k];
            lv[k] = kept[k] ? tkw[b * 8 + k] : 0.0f;
        } else { kept[k] = 0; idx[k] = -1; lv[k] = -1e30f; }
    }
    float mx = -1e30f;
#pragma unroll
    for (int k = 0; k < 8; k++) if (k < maxk) mx = fmaxf(mx, lv[k]);
    float s = 0.0f; float ev[8];
#pragma unroll
    for (int k = 0; k < 8; k++) { ev[k] = (k < maxk) ? expf(lv[k] - mx) : 0.0f; s += ev[k]; }
    float inv = 1.0f / s;
    float Wr[8] = {0, 0, 0, 0, 0, 0, 0, 0};
#pragma unroll
    for (int k = 0; k < 8; k++) {
        if (kept[k]) {
            float v = ev[k] * inv;
#pragma unroll
            for (int e = 0; e < 8; e++) Wr[e] += (idx[k] == e) ? v : 0.0f;
        }
    }
#pragma unroll
    for (int e = 0; e < 8; e++) ws[WS_WMAT + b * 8 + e] = Wr[e];
}

// ---- L2 regularizer ----
__global__ __launch_bounds__(256) void k_reg(const float* __restrict__ ew,
                                             const float* __restrict__ eb,
                                             float* __restrict__ ws)
{
    __shared__ float red[256];
    const size_t t0 = (size_t)blockIdx.x * 256 + threadIdx.x;
    const size_t stride = (size_t)gridDim.x * 256 * 4;
    float s = 0.0f;
    for (size_t i = t0 * 4; i < 8388608; i += stride) {
        float4 v = *(const float4*)(ew + i);
        s += v.x * v.x + v.y * v.y + v.z * v.z + v.w * v.w;
    }
    if (t0 < 2048) {
        float4 v = ((const float4*)eb)[t0];
        s += v.x * v.x + v.y * v.y + v.z * v.z + v.w * v.w;
    }
    red[threadIdx.x] = s;
    __syncthreads();
    for (int off = 128; off > 0; off >>= 1) {
        if (threadIdx.x < off) red[threadIdx.x] += red[threadIdx.x + off];
        __syncthreads();
    }
    if (threadIdx.x == 0) atomicAdd(ws + WS_REG, red[0]);
}

// ---- expert mix GEMM (split-K=16) ----
__global__ __launch_bounds__(256) void k_gemm(const float* __restrict__ ew,
                                              float* __restrict__ ws)
{
    __shared__ float a_s[32 * 128];
    __shared__ float b_s[32 * 64];
    __shared__ float w_s[1024];
    const int blk = blockIdx.x;
    const int ks = blk >> 4, dt = blk & 15;
    const int tid = threadIdx.x;
    const int tb = tid >> 3, td = tid & 7;
    for (int i = tid; i < 1024; i += 256) w_s[i] = ws[WS_WMAT + i];
    float acc[4][8];
#pragma unroll
    for (int i = 0; i < 4; i++)
#pragma unroll
        for (int j = 0; j < 8; j++) acc[i][j] = 0.0f;

    const float* pxt = ws + WS_PXT;
    for (int kt = 0; kt < 512; kt += 32) {
        __syncthreads();
        for (int idx = tid; idx < 4096; idx += 256) {
            int kk = idx >> 7, b = idx & 127;
            int k = ks * 512 + kt + kk;
            int e = k >> 10, h = k & 1023;
            a_s[kk * 128 + b] = w_s[b * 8 + e] * pxt[(size_t)h * 128 + b];
        }
        for (int idx = tid; idx < 2048; idx += 256) {
            int kk = idx >> 6, d = idx & 63;
            b_s[kk * 64 + d] = ew[(size_t)(ks * 512 + kt + kk) * 1024 + dt * 64 + d];
        }
        __syncthreads();
#pragma unroll 4
        for (int kk = 0; kk < 32; kk++) {
            float4 av = *(const float4*)&a_s[kk * 128 + tb * 4];
            float4 b0 = *(const float4*)&b_s[kk * 64 + td * 8];
            float4 b1 = *(const float4*)&b_s[kk * 64 + td * 8 + 4];
            float aa[4] = {av.x, av.y, av.z, av.w};
            float bb[8] = {b0.x, b0.y, b0.z, b0.w, b1.x, b1.y, b1.z, b1.w};
#pragma unroll
            for (int i = 0; i < 4; i++)
#pragma unroll
                for (int j = 0; j < 8; j++) acc[i][j] = fmaf(aa[i], bb[j], acc[i][j]);
        }
    }
    float* outp = ws + WS_PART + (size_t)blk * 8192;
#pragma unroll
    for (int i = 0; i < 4; i++) {
        int bb = tb * 4 + i;
        float4 v0 = make_float4(acc[i][0], acc[i][1], acc[i][2], acc[i][3]);
        float4 v1 = make_float4(acc[i][4], acc[i][5], acc[i][6], acc[i][7]);
        *(float4*)(outp + bb * 64 + td * 8) = v0;
        *(float4*)(outp + bb * 64 + td * 8 + 4) = v1;
    }
}

// ---- split-K reduce + weighted expert bias + scalar outputs ----
__global__ __launch_bounds__(256) void k_final(const float* __restrict__ eb,
                                               const float* __restrict__ ws,
                                               float* __restrict__ out)
{
    int id = blockIdx.x * 256 + threadIdx.x;   // 131072
    int b = id >> 10, d = id & 1023;
    int dt = d >> 6, dd = d & 63;
    float s = 0.0f;
#pragma unroll
    for (int ks = 0; ks < 16; ks++)
        s += ws[WS_PART + ((size_t)(ks * 16 + dt) * 128 + b) * 64 + dd];
    float bias = 0.0f;
#pragma unroll
    for (int e = 0; e < 8; e++)
        bias += ws[WS_WMAT + b * 8 + e] * eb[(size_t)e * 1024 + d];
    out[id] = s + bias;
    if (blockIdx.x == 0) {
        int t = threadIdx.x;
        if (t == 0) out[131072] = 0.005f * ws[WS_VARU] + 1e-6f * ws[WS_REG];
        else if (t >= 1 && t < 9)  out[131072 + t] = ws[WS_USAGE + t - 1];
        else if (t >= 9 && t < 17) out[131072 + t] = ws[WS_CNT + t - 9];
    }
}

extern "C" void kernel_launch(void* const* d_in, const int* in_sizes, int n_in,
                              void* d_out, int out_size, void* d_ws, size_t ws_size,
                              hipStream_t stream)
{
    const float* x   = (const float*)d_in[0];
    const float* cw  = (const float*)d_in[1];
    const float* cb  = (const float*)d_in[2];
    const float* bng = (const float*)d_in[3];
    const float* bnb = (const float*)d_in[4];
    const float* f1w = (const float*)d_in[5];
    const float* f1b = (const float*)d_in[6];
    const float* f2w = (const float*)d_in[7];
    const float* f2b = (const float*)d_in[8];
    const float* ew  = (const float*)d_in[9];
    const float* eb  = (const float*)d_in[10];
    float* ws  = (float*)d_ws;
    float* out = (float*)d_out;

    k_init    <<<1, 1, 0, stream>>>(ws);
    k_wsplit  <<<768, 256, 0, stream>>>(cw, ws);
    k_convmfma<<<dim3(4, 128), 256, 0, stream>>>(x, cb, ws);
    k_poolx   <<<512, 256, 0, stream>>>(ws);
    k_bn      <<<4, 256, 0, stream>>>(bng, bnb, ws);
    k_fc1     <<<128, 128, 0, stream>>>(f1w, f1b, ws);
    k_router  <<<1, 128, 0, stream>>>(f2w, f2b, ws);
    k_cap     <<<8, 128, 0, stream>>>(ws);
    k_comb    <<<1, 128, 0, stream>>>(ws);
    k_reg     <<<512, 256, 0, stream>>>(ew, eb, ws);
    k_gemm    <<<256, 256, 0, stream>>>(ew, ws);
    k_final   <<<512, 256, 0, stream>>>(eb, ws, out);
}